// Round 8
// baseline (814.348 us; speedup 1.0000x reference)
//
#include <hip/hip_runtime.h>
#include <math.h>

// ---------------------------------------------------------------------------
// GCNRecommender: 3x GCNConv (D=64) + linear head. N=300K nodes, E=1.2M edges.
// R12: 4 clean GEMM structures all pinned at 76-86us (R0 LDS-tile, R5
// broadcast, R10 reg-dbuf, R11 scalar-W) -- per-dispatch microstructure is a
// local minimum. This round DELETES the GEMMs via aggregate-first algebra:
//   layer: out[c] = dinv_c*(z@W)+b,  z[c] = sum_in dinv_r*X[r] + dinv_c*X[c]
// with pre-scaled storage A'[c] = dinv_c*relu(out[c]) so layers 2-3 aggregate
// with plain adds; head folded into conv3 via W' = W3@linW, b' = b3@linW+linb
// (tiny precompute kernel). 3 fused gather+transform kernels replace 3
// gathers + 4 GEMMs. Transform: z staged through wave-local LDS row (no
// barrier), each lane computes its 4 cols: 16 broadcast ds_read_b128 +
// 64 L1-hot W loads + 256 FMA -- bounded, spill-proof. All fp32.
// ---------------------------------------------------------------------------

// ---- CSR build -------------------------------------------------------------

__global__ void k_hist(const int* __restrict__ col, int* __restrict__ cnt, int e) {
    int i = blockIdx.x * blockDim.x + threadIdx.x;
    if (i < e) atomicAdd(&cnt[col[i]], 1);
}

// exclusive scan, 1024 elems/block (256 thr x 4)
__global__ void k_scan1(const int* __restrict__ cnt, int* __restrict__ offs,
                        int* __restrict__ bsum, int n) {
    __shared__ int s[256];
    const int t = threadIdx.x;
    const int base = blockIdx.x * 1024 + t * 4;
    int v[4], sum = 0;
    #pragma unroll
    for (int k = 0; k < 4; ++k) {
        v[k] = (base + k < n) ? cnt[base + k] : 0;
        sum += v[k];
    }
    s[t] = sum;
    __syncthreads();
    #pragma unroll
    for (int off = 1; off < 256; off <<= 1) {
        int x = (t >= off) ? s[t - off] : 0;
        __syncthreads();
        s[t] += x;
        __syncthreads();
    }
    int run = s[t] - sum;
    #pragma unroll
    for (int k = 0; k < 4; ++k) {
        if (base + k < n) offs[base + k] = run;
        run += v[k];
    }
    if (t == 255) bsum[blockIdx.x] = s[255];
}

__global__ void k_scan2(int* __restrict__ bsum, int nb) {
    __shared__ int s[512];
    const int t = threadIdx.x;
    int v = (t < nb) ? bsum[t] : 0;
    s[t] = v;
    __syncthreads();
    #pragma unroll
    for (int off = 1; off < 512; off <<= 1) {
        int x = (t >= off) ? s[t - off] : 0;
        __syncthreads();
        s[t] += x;
        __syncthreads();
    }
    if (t < nb) bsum[t] = s[t] - v;
}

__global__ void k_scan3(int* __restrict__ offs, const int* __restrict__ bsum,
                        int n, int e) {
    int i = blockIdx.x * blockDim.x + threadIdx.x;
    if (i < n) offs[i] += bsum[i >> 10];
    if (i == 0) offs[n] = e;
}

__global__ void k_fill(const int* __restrict__ row, const int* __restrict__ col,
                       const int* __restrict__ offs, int* __restrict__ cur,
                       int* __restrict__ elist, int e) {
    int i = blockIdx.x * blockDim.x + threadIdx.x;
    if (i < e) {
        int c = col[i];
        int pos = offs[c] + atomicAdd(&cur[c], 1);
        elist[pos] = row[i];
    }
}

__global__ void k_dinv(const int* __restrict__ cnt, float* __restrict__ dinv, int n) {
    int i = blockIdx.x * blockDim.x + threadIdx.x;
    if (i < n) dinv[i] = 1.0f / sqrtf((float)(cnt[i] + 1));  // +1 self-loop
}

// ---- head fold: Wp = W3 @ linW, bp = b3 @ linW + linb (1 block) ------------
__global__ void k_wmul(const float* __restrict__ W3, const float* __restrict__ linW,
                       const float* __restrict__ b3, const float* __restrict__ linb,
                       float* __restrict__ Wp, float* __restrict__ bp) {
    const int t = threadIdx.x;   // 256 threads
    #pragma unroll 1
    for (int i = 0; i < 16; ++i) {
        int idx = t * 16 + i;          // 4096 entries
        int k = idx >> 6, c = idx & 63;
        float s = 0.f;
        for (int j = 0; j < 64; ++j) s = fmaf(W3[k * 64 + j], linW[j * 64 + c], s);
        Wp[idx] = s;
    }
    if (t < 64) {
        float s = linb[t];
        for (int j = 0; j < 64; ++j) s = fmaf(b3[j], linW[j * 64 + t], s);
        bp[t] = s;
    }
}

// ---- fused GCN layer: aggregate (CSR gather) + 64x64 transform -------------
// 16 lanes per node (4 nodes/wave, 16 nodes/block). Lane q owns cols 4q..4q+3.
//   z[c] = sum_{r in in(c)} w_r * S[r] + w_c * S[c]
//     conv1 (ut!=null): S = embeddings via uid/iid, w_r = dinv_r, w_c = dinv_c
//     conv2/3:          S = prev A' (pre-scaled),  w_r = w_c = 1
//   o = z @ W   (z staged through wave-local LDS row; lane computes 4 cols)
//   !is_last: OUT[c] = dinv_c * relu(dinv_c*o + b)   (pre-scaled for next agg)
//   is_last:  OUT[c] = dinv_c*o + b                  (final, W=Wp b=bp)
__device__ __forceinline__ const float4* rowp(const float* __restrict__ SRC,
        const int* __restrict__ uid, const int* __restrict__ iid,
        const float* __restrict__ ut, const float* __restrict__ it,
        int r, int u) {
    if (ut != nullptr) {
        const float* p = (r < u) ? (ut + (size_t)uid[r] * 64)
                                 : (it + (size_t)iid[r - u] * 64);
        return (const float4*)p;
    }
    return (const float4*)(SRC + (size_t)r * 64);
}

__launch_bounds__(256)
__global__ void k_fused(const int* __restrict__ offs, const int* __restrict__ elist,
                        const float* __restrict__ dinv,
                        const float* __restrict__ SRC,
                        const int* __restrict__ uid, const int* __restrict__ iid,
                        const float* __restrict__ ut, const float* __restrict__ it,
                        const float* __restrict__ W, const float* __restrict__ bias,
                        float4* __restrict__ OUT4, int n, int u, int is_last) {
    __shared__ float Z[16][68];                  // 4.3 KB; row/wave-local
    const int t = threadIdx.x;
    const int nid = blockIdx.x * 16 + (t >> 4);
    const int q = t & 15;
    const int gl = t >> 4;                       // group within block
    const int gbase = t & 48;                    // first lane of group in wave
    if (nid >= n) return;                        // whole group uniform

    const int beg = offs[nid];
    const int end = offs[nid + 1];
    const int deg = end - beg;
    const bool first = (ut != nullptr);

    // early independent loads
    const float dc = dinv[nid];
    float4 bb = ((const float4*)bias)[q];
    float4 self = rowp(SRC, uid, iid, ut, it, nid, u)[q];
    int eidx = (q < deg) ? elist[beg + q] : 0;   // safe default row 0

    int m = deg;
    m = max(m, __shfl_xor(m, 16, 64));
    m = max(m, __shfl_xor(m, 32, 64));
    m = min(m, 16);

    // ---- aggregate ----
    float4 acc;
    if (first) {
        acc.x = dc * self.x; acc.y = dc * self.y;
        acc.z = dc * self.z; acc.w = dc * self.w;
    } else {
        acc = self;
    }

    int j = 0;
    for (; j + 4 <= m; j += 4) {
        int r0 = __shfl(eidx, gbase + j + 0, 64);
        int r1 = __shfl(eidx, gbase + j + 1, 64);
        int r2 = __shfl(eidx, gbase + j + 2, 64);
        int r3 = __shfl(eidx, gbase + j + 3, 64);
        float4 v0 = rowp(SRC, uid, iid, ut, it, r0, u)[q];
        float4 v1 = rowp(SRC, uid, iid, ut, it, r1, u)[q];
        float4 v2 = rowp(SRC, uid, iid, ut, it, r2, u)[q];
        float4 v3 = rowp(SRC, uid, iid, ut, it, r3, u)[q];
        if (first) {
            float s0 = dinv[r0], s1 = dinv[r1], s2 = dinv[r2], s3 = dinv[r3];
            if (j + 0 < deg) { acc.x = fmaf(s0, v0.x, acc.x); acc.y = fmaf(s0, v0.y, acc.y);
                               acc.z = fmaf(s0, v0.z, acc.z); acc.w = fmaf(s0, v0.w, acc.w); }
            if (j + 1 < deg) { acc.x = fmaf(s1, v1.x, acc.x); acc.y = fmaf(s1, v1.y, acc.y);
                               acc.z = fmaf(s1, v1.z, acc.z); acc.w = fmaf(s1, v1.w, acc.w); }
            if (j + 2 < deg) { acc.x = fmaf(s2, v2.x, acc.x); acc.y = fmaf(s2, v2.y, acc.y);
                               acc.z = fmaf(s2, v2.z, acc.z); acc.w = fmaf(s2, v2.w, acc.w); }
            if (j + 3 < deg) { acc.x = fmaf(s3, v3.x, acc.x); acc.y = fmaf(s3, v3.y, acc.y);
                               acc.z = fmaf(s3, v3.z, acc.z); acc.w = fmaf(s3, v3.w, acc.w); }
        } else {
            if (j + 0 < deg) { acc.x += v0.x; acc.y += v0.y; acc.z += v0.z; acc.w += v0.w; }
            if (j + 1 < deg) { acc.x += v1.x; acc.y += v1.y; acc.z += v1.z; acc.w += v1.w; }
            if (j + 2 < deg) { acc.x += v2.x; acc.y += v2.y; acc.z += v2.z; acc.w += v2.w; }
            if (j + 3 < deg) { acc.x += v3.x; acc.y += v3.y; acc.z += v3.z; acc.w += v3.w; }
        }
    }
    for (; j < m; ++j) {
        int r = __shfl(eidx, gbase + j, 64);
        float4 v = rowp(SRC, uid, iid, ut, it, r, u)[q];
        if (j < deg) {
            float s = first ? dinv[r] : 1.0f;
            acc.x = fmaf(s, v.x, acc.x); acc.y = fmaf(s, v.y, acc.y);
            acc.z = fmaf(s, v.z, acc.z); acc.w = fmaf(s, v.w, acc.w);
        }
    }
    // rare tail (deg > 16)
    for (int jj = beg + 16; jj < end; ++jj) {
        int r = elist[jj];
        float4 v = rowp(SRC, uid, iid, ut, it, r, u)[q];
        float s = first ? dinv[r] : 1.0f;
        acc.x = fmaf(s, v.x, acc.x); acc.y = fmaf(s, v.y, acc.y);
        acc.z = fmaf(s, v.z, acc.z); acc.w = fmaf(s, v.w, acc.w);
    }

    // ---- transform: o[4q..4q+3] = z @ W (cols 4q..4q+3) ----
    // z staged in wave-local LDS row; groups are intra-wave -> DS in-order
    // per wave, no barrier needed. Broadcast reads are conflict-free (row
    // stride 68: 4 groups land on distinct banks).
    *(float4*)&Z[gl][q * 4] = acc;

    float4 o = make_float4(0.f, 0.f, 0.f, 0.f);
    const float* Wl = W + q * 4;                 // lane's col base
    #pragma unroll 2
    for (int kk = 0; kk < 16; ++kk) {
        float4 z = *(const float4*)&Z[gl][kk * 4];   // group broadcast
        const float* wb = Wl + kk * 256;             // rows 4kk..4kk+3
        float4 w0 = *(const float4*)(wb);
        float4 w1 = *(const float4*)(wb + 64);
        float4 w2 = *(const float4*)(wb + 128);
        float4 w3 = *(const float4*)(wb + 192);
        o.x = fmaf(z.x, w0.x, o.x); o.y = fmaf(z.x, w0.y, o.y);
        o.z = fmaf(z.x, w0.z, o.z); o.w = fmaf(z.x, w0.w, o.w);
        o.x = fmaf(z.y, w1.x, o.x); o.y = fmaf(z.y, w1.y, o.y);
        o.z = fmaf(z.y, w1.z, o.z); o.w = fmaf(z.y, w1.w, o.w);
        o.x = fmaf(z.z, w2.x, o.x); o.y = fmaf(z.z, w2.y, o.y);
        o.z = fmaf(z.z, w2.z, o.z); o.w = fmaf(z.z, w2.w, o.w);
        o.x = fmaf(z.w, w3.x, o.x); o.y = fmaf(z.w, w3.y, o.y);
        o.z = fmaf(z.w, w3.z, o.z); o.w = fmaf(z.w, w3.w, o.w);
    }

    // ---- epilogue ----
    float4 res;
    if (!is_last) {
        // out = dc*o + b; h = relu(out); store dc*h (pre-scaled for next layer)
        float ox = fmaf(dc, o.x, bb.x), oy = fmaf(dc, o.y, bb.y);
        float oz = fmaf(dc, o.z, bb.z), ow = fmaf(dc, o.w, bb.w);
        res.x = dc * fmaxf(ox, 0.f); res.y = dc * fmaxf(oy, 0.f);
        res.z = dc * fmaxf(oz, 0.f); res.w = dc * fmaxf(ow, 0.f);
    } else {
        res.x = fmaf(dc, o.x, bb.x); res.y = fmaf(dc, o.y, bb.y);
        res.z = fmaf(dc, o.z, bb.z); res.w = fmaf(dc, o.w, bb.w);
    }
    OUT4[(size_t)nid * 16 + q] = res;
}

// ---------------------------------------------------------------------------

extern "C" void kernel_launch(void* const* d_in, const int* in_sizes, int n_in,
                              void* d_out, int out_size, void* d_ws, size_t ws_size,
                              hipStream_t stream) {
    const int*   user_ids = (const int*)d_in[0];
    const int*   item_ids = (const int*)d_in[1];
    const int*   edge     = (const int*)d_in[2];
    const float* ut   = (const float*)d_in[4];
    const float* it   = (const float*)d_in[5];
    const float* W1   = (const float*)d_in[6];
    const float* b1   = (const float*)d_in[7];
    const float* W2   = (const float*)d_in[8];
    const float* b2   = (const float*)d_in[9];
    const float* W3   = (const float*)d_in[10];
    const float* b3   = (const float*)d_in[11];
    const float* linW = (const float*)d_in[12];
    const float* linb = (const float*)d_in[13];

    const int u = in_sizes[0];
    const int iN = in_sizes[1];
    const int e = in_sizes[2] / 2;
    const int n = u + iN;

    // workspace layout
    float* A    = (float*)d_ws;                       // [n,64] layer-2 feats
    float* dinv = A + (size_t)n * 64;                 // [n]
    int*   cnt  = (int*)(dinv + n);                   // [n]  (reused as cursor)
    int*   offs = cnt + n;                            // [n+1]
    int*   bsum = offs + n + 1;                       // [nb]
    int*   elist = bsum + 1024;                       // [e]
    float* Wp   = (float*)(elist + e);                // [64*64] W3@linW
    float* bp   = Wp + 64 * 64;                       // [64]
    float* A1   = (float*)d_out;                      // conv1 out (pre-scaled)

    const int* erow = edge;
    const int* ecol = edge + e;

    const int B = 256;
    const int nb = (n + 1023) / 1024;

    // ---- CSR build + dinv + head fold ----
    hipMemsetAsync(cnt, 0, (size_t)n * sizeof(int), stream);
    k_hist<<<(e + B - 1) / B, B, 0, stream>>>(ecol, cnt, e);
    k_scan1<<<nb, 256, 0, stream>>>(cnt, offs, bsum, n);
    k_scan2<<<1, 512, 0, stream>>>(bsum, nb);
    k_scan3<<<(n + B - 1) / B, B, 0, stream>>>(offs, bsum, n, e);
    k_dinv<<<(n + B - 1) / B, B, 0, stream>>>(cnt, dinv, n);
    hipMemsetAsync(cnt, 0, (size_t)n * sizeof(int), stream);  // cursor
    k_fill<<<(e + B - 1) / B, B, 0, stream>>>(erow, ecol, offs, cnt, elist, e);
    k_wmul<<<1, 256, 0, stream>>>(W3, linW, b3, linb, Wp, bp);

    const int fgrid = (n + 15) / 16;  // 16 nodes/block

    // conv1: embeddings (dinv_r-scaled) -> A1 (=d_out, pre-scaled, relu)
    k_fused<<<fgrid, B, 0, stream>>>(offs, elist, dinv, nullptr,
                                     user_ids, item_ids, ut, it,
                                     W1, b1, (float4*)A1, n, u, 0);
    // conv2: A1 -> A (pre-scaled, relu)
    k_fused<<<fgrid, B, 0, stream>>>(offs, elist, dinv, A1,
                                     nullptr, nullptr, nullptr, nullptr,
                                     W2, b2, (float4*)A, n, u, 0);
    // conv3 + head (W'=W3@linW, b'=b3@linW+linb): A -> d_out (final)
    k_fused<<<fgrid, B, 0, stream>>>(offs, elist, dinv, A,
                                     nullptr, nullptr, nullptr, nullptr,
                                     Wp, bp, (float4*)d_out, n, u, 1);
}